// Round 15
// baseline (205.598 us; speedup 1.0000x reference)
//
#include <hip/hip_runtime.h>
#include <hip/hip_bf16.h>
#include <cstdint>

typedef _Float16 half2v __attribute__((ext_vector_type(2)));

#define EPB   16        // entities per bucket
#define MAXNB 1024      // max buckets for bin LDS histogram (NUMENT <= 16384)
#define FPB   8192      // facts per bin-block (1024 thr x FPT 8) -> 245 blocks
#define FPT   8         // facts per thread (CONSECUTIVE -> dwordx4 loads)
#define GRAN  16        // run reservation granule: 16 entries = 64B sector
#define MARK  0xFFFFFFFFu
#define SORTCAP 7168    // gather LDS payload capacity (u32 -> 28 KB)
#define CPT   14        // SORTCAP / 512 register-held entries per thread
#define OVFCAP 65536    // overflow list capacity (512 KB; statistically unreachable)

// payload u32: [31:28]=local entity (4b) | [27:16]=rel (12b, R<4096) | [15:0]=fp16(val)
// overflow uint2: x = (bucket<<16) | (le<<12) | rel, y = fp32(val) bits

// ---------------------------------------------------------------------------
// Kernel 1: bin endpoints into per-bucket lists + appended RWB table build.
// r14 PMC: WRITE_SIZE 71MB for 18.5MB payload (4x partial-sector write
// amplification + cross-XCD sector sharing) at 1.2TB/s ~ the whole 59us.
// Fix: FPB 8192 (runs ~16 entries) + per-(block,bucket) reservations rounded
// to 16-entry (64B) multiples, pads filled with MARK. Every run starts
// 64B-aligned, every touched sector is fully dirty -> no partial writeback,
// no cross-block sector sharing.
// ---------------------------------------------------------------------------
__global__ __launch_bounds__(1024) void bin_rwb_kernel(
    const int* __restrict__ heads, const int* __restrict__ tails,
    const int* __restrict__ rels, const float* __restrict__ val,
    const float* __restrict__ relf, const float* __restrict__ W,
    const float* __restrict__ bias, _Float16* __restrict__ rwb,
    int* __restrict__ gcnt, int* __restrict__ ovfcnt, uint2* __restrict__ ovf,
    unsigned* __restrict__ slots,
    int E, int R, int NB, int CAPB) {
    __shared__ int cnt[MAXNB];
    __shared__ int gbase[MAXNB];
    const int t = threadIdx.x;
    for (int k = t; k < NB; k += 1024) cnt[k] = 0;
    __syncthreads();

    const int i0 = blockIdx.x * FPB + t * FPT;
    unsigned payT[FPT], payH[FPT], prT[FPT], prH[FPT];
#pragma unroll
    for (int u = 0; u < FPT; ++u) { prT[u] = 0xFFFFFFFFu; prH[u] = 0xFFFFFFFFu; }

    int tl[FPT], hd[FPT], rr[FPT];
    float vv[FPT];
    int nval = 0;
    if (i0 + FPT <= E) {
        *reinterpret_cast<int4*>(&tl[0]) = *reinterpret_cast<const int4*>(tails + i0);
        *reinterpret_cast<int4*>(&tl[4]) = *reinterpret_cast<const int4*>(tails + i0 + 4);
        *reinterpret_cast<int4*>(&hd[0]) = *reinterpret_cast<const int4*>(heads + i0);
        *reinterpret_cast<int4*>(&hd[4]) = *reinterpret_cast<const int4*>(heads + i0 + 4);
        *reinterpret_cast<int4*>(&rr[0]) = *reinterpret_cast<const int4*>(rels + i0);
        *reinterpret_cast<int4*>(&rr[4]) = *reinterpret_cast<const int4*>(rels + i0 + 4);
        *reinterpret_cast<float4*>(&vv[0]) = *reinterpret_cast<const float4*>(val + i0);
        *reinterpret_cast<float4*>(&vv[4]) = *reinterpret_cast<const float4*>(val + i0 + 4);
        nval = FPT;
    } else {
#pragma unroll
        for (int u = 0; u < FPT; ++u) {
            const int i = i0 + u;
            if (i < E) {
                tl[u] = tails[i]; hd[u] = heads[i];
                rr[u] = rels[i];  vv[u] = val[i];
                nval = u + 1;
            }
        }
    }
#pragma unroll
    for (int u = 0; u < FPT; ++u) {
        if (u < nval) {
            const unsigned hv =
                (unsigned)__builtin_bit_cast(unsigned short, (_Float16)vv[u]);
            const int bt = tl[u] >> 4, bh = hd[u] >> 4;      // EPB = 16
            payT[u] = ((unsigned)(tl[u] & 15) << 28) | ((unsigned)rr[u] << 16) | hv;
            payH[u] = ((unsigned)(hd[u] & 15) << 28) | ((unsigned)rr[u] << 16) | hv;
            const int rt = atomicAdd(&cnt[bt], 1);           // LDS int rank (native)
            const int rh = atomicAdd(&cnt[bh], 1);
            prT[u] = ((unsigned)bt << 16) | (unsigned)rt;    // rank < 65536 fits
            prH[u] = ((unsigned)bh << 16) | (unsigned)rh;
        }
    }
    __syncthreads();
    for (int k = t; k < NB; k += 1024) {
        const int c = cnt[k];
        const int rc = (c + GRAN - 1) & ~(GRAN - 1);         // 64B-aligned reservation
        gbase[k] = rc ? atomicAdd(&gcnt[k], rc) : 0;         // base is multiple of 16
    }
    __syncthreads();
#pragma unroll
    for (int u = 0; u < FPT; ++u) {
        if (prT[u] != 0xFFFFFFFFu) {
            {
                const int b1 = (int)(prT[u] >> 16);
                const int pos = gbase[b1] + (int)(prT[u] & 0xFFFFu);
                if (pos < CAPB) slots[(size_t)b1 * CAPB + pos] = payT[u];
                else {
                    const int op = atomicAdd(ovfcnt, 1);
                    if (op < OVFCAP) {
                        uint2 o;
                        o.x = ((unsigned)b1 << 16) | ((payT[u] >> 28) << 12) |
                              ((payT[u] >> 16) & 0xFFFu);
                        o.y = __float_as_uint(vv[u]);
                        ovf[op] = o;
                    }
                }
            }
            {
                const int b1 = (int)(prH[u] >> 16);
                const int pos = gbase[b1] + (int)(prH[u] & 0xFFFFu);
                if (pos < CAPB) slots[(size_t)b1 * CAPB + pos] = payH[u];
                else {
                    const int op = atomicAdd(ovfcnt, 1);
                    if (op < OVFCAP) {
                        uint2 o;
                        o.x = ((unsigned)b1 << 16) | ((payH[u] >> 28) << 12) |
                              ((payH[u] >> 16) & 0xFFFu);
                        o.y = __float_as_uint(vv[u]);
                        ovf[op] = o;
                    }
                }
            }
        }
    }
    // pad the tail of each reserved run with MARK (same sectors as the run ->
    // no extra traffic; gather Phase A drops them with one compare)
    for (int k = t; k < NB; k += 1024) {
        const int c = cnt[k];
        const int rc = (c + GRAN - 1) & ~(GRAN - 1);
        const int gb = gbase[k];
        for (int p = c; p < rc; ++p) {
            const int pos = gb + p;
            if (pos < CAPB) slots[(size_t)k * CAPB + pos] = MARK;
        }
    }

    // ---- appended: RWB table (grid-strided, 8 rows / block-iteration) ----
    const int rsub = t >> 7;            // 0..7
    const int col  = t & 127;
    for (int row0 = blockIdx.x * 8; row0 < R; row0 += gridDim.x * 8) {
        const int row = row0 + rsub;
        if (row < R) {
            const float4* rp = reinterpret_cast<const float4*>(relf + (size_t)row * 128);
            const float4* wp = reinterpret_cast<const float4*>(W + (size_t)col * 128);
            float acc = 0.f;
#pragma unroll
            for (int i = 0; i < 32; ++i) {
                float4 a = rp[i], w = wp[i];
                acc += a.x * w.x + a.y * w.y + a.z * w.z + a.w * w.w;
            }
            rwb[(size_t)row * 128 + col] = (_Float16)(acc + bias[col]);
        }
    }
}

// batch-of-8 for one entity: named registers, no rotation copies
#define GATHER_BATCH8(S0, J, A0, A1)                                            \
    {                                                                           \
        uint2 qp[4];                                                            \
        _Pragma("unroll")                                                       \
        for (int u = 0; u < 4; ++u)                                             \
            qp[u] = *reinterpret_cast<const uint2*>(&se[(S0) + (J) + 2 * u]);   \
        unsigned qs[8];                                                         \
        _Pragma("unroll")                                                       \
        for (int u = 0; u < 4; ++u) {                                           \
            qs[2 * u]     = __builtin_amdgcn_readfirstlane(qp[u].x);            \
            qs[2 * u + 1] = __builtin_amdgcn_readfirstlane(qp[u].y);            \
        }                                                                       \
        unsigned rw[8];                                                         \
        _Pragma("unroll")                                                       \
        for (int u = 0; u < 8; ++u) {                                           \
            const _Float16* rowp = rwb + (size_t)((qs[u] >> 16) & 0xFFFu) * 128;\
            rw[u] = *reinterpret_cast<const unsigned*>(rowp + loff);            \
        }                                                                       \
        _Pragma("unroll")                                                       \
        for (int u = 0; u < 8; ++u) {                                           \
            asm("v_fma_mix_f32 %[d], %[s0], %[s1], %[d] op_sel:[0,0,0] op_sel_hi:[1,1,0]" \
                : [d]"+v"(A0) : [s0]"s"(qs[u]), [s1]"v"(rw[u]));                \
            asm("v_fma_mix_f32 %[d], %[s0], %[s1], %[d] op_sel:[0,1,0] op_sel_hi:[1,1,0]" \
                : [d]"+v"(A1) : [s0]"s"(qs[u]), [s1]"v"(rw[u]));                \
        }                                                                       \
    }

// joint batch: both entities' loads issued before either's FMAs -> 2 chains
#define GATHER_BATCH8x2(S0A, JA, A0A, A1A, S0B, JB, A0B, A1B)                   \
    {                                                                           \
        uint2 qpa[4], qpb[4];                                                   \
        _Pragma("unroll")                                                       \
        for (int u = 0; u < 4; ++u) {                                           \
            qpa[u] = *reinterpret_cast<const uint2*>(&se[(S0A) + (JA) + 2 * u]);\
            qpb[u] = *reinterpret_cast<const uint2*>(&se[(S0B) + (JB) + 2 * u]);\
        }                                                                       \
        unsigned qsa[8], qsb[8];                                                \
        _Pragma("unroll")                                                       \
        for (int u = 0; u < 4; ++u) {                                           \
            qsa[2 * u]     = __builtin_amdgcn_readfirstlane(qpa[u].x);          \
            qsa[2 * u + 1] = __builtin_amdgcn_readfirstlane(qpa[u].y);          \
            qsb[2 * u]     = __builtin_amdgcn_readfirstlane(qpb[u].x);          \
            qsb[2 * u + 1] = __builtin_amdgcn_readfirstlane(qpb[u].y);          \
        }                                                                       \
        unsigned rwa[8], rwb_[8];                                               \
        _Pragma("unroll")                                                       \
        for (int u = 0; u < 8; ++u) {                                           \
            rwa[u] = *reinterpret_cast<const unsigned*>(                        \
                rwb + (size_t)((qsa[u] >> 16) & 0xFFFu) * 128 + loff);          \
            rwb_[u] = *reinterpret_cast<const unsigned*>(                       \
                rwb + (size_t)((qsb[u] >> 16) & 0xFFFu) * 128 + loff);          \
        }                                                                       \
        _Pragma("unroll")                                                       \
        for (int u = 0; u < 8; ++u) {                                           \
            asm("v_fma_mix_f32 %[d], %[s0], %[s1], %[d] op_sel:[0,0,0] op_sel_hi:[1,1,0]" \
                : [d]"+v"(A0A) : [s0]"s"(qsa[u]), [s1]"v"(rwa[u]));             \
            asm("v_fma_mix_f32 %[d], %[s0], %[s1], %[d] op_sel:[0,1,0] op_sel_hi:[1,1,0]" \
                : [d]"+v"(A1A) : [s0]"s"(qsa[u]), [s1]"v"(rwa[u]));             \
            asm("v_fma_mix_f32 %[d], %[s0], %[s1], %[d] op_sel:[0,0,0] op_sel_hi:[1,1,0]" \
                : [d]"+v"(A0B) : [s0]"s"(qsb[u]), [s1]"v"(rwb_[u]));            \
            asm("v_fma_mix_f32 %[d], %[s0], %[s1], %[d] op_sel:[0,1,0] op_sel_hi:[1,1,0]" \
                : [d]"+v"(A1B) : [s0]"s"(qsb[u]), [s1]"v"(rwb_[u]));            \
        }                                                                       \
    }

// ---------------------------------------------------------------------------
// Kernel 2: gather — one 512-thread block per 16-entity bucket.
// Phase A: counting sort into 28KB LDS, DROPPING pad markers (one compare).
// Phase B: r14's proven joint-batch loop, byte-identical.
// ---------------------------------------------------------------------------
__global__ __launch_bounds__(512) void gather_kernel(
    const unsigned* __restrict__ slots, const int* __restrict__ gcnt,
    const int* __restrict__ ovfcnt, const uint2* __restrict__ ovf,
    const _Float16* __restrict__ rwb, float* __restrict__ out,
    int NUMENT, int CAPB) {
    __shared__ unsigned se[SORTCAP];           // 28 KB sorted payloads
    __shared__ int cnt[EPB], basep[EPB];
    const int t = threadIdx.x;
    const int b = blockIdx.x;
    if (t < EPB) cnt[t] = 0;
    __syncthreads();

    int deg = gcnt[b];
    if (deg > CAPB) deg = CAPB;        // overflow entries went to ovf list
    const unsigned* sl = slots + (size_t)b * CAPB;

    // Phase A: coalesced load, drop markers, LDS rank, sorted placement
    unsigned e[CPT];
    int rk[CPT];
#pragma unroll
    for (int u = 0; u < CPT; ++u) {
        const int k = t + u * 512;
        rk[u] = -1;
        if (k < deg) {
            e[u] = sl[k];
            if (e[u] != MARK)
                rk[u] = atomicAdd(&cnt[(int)(e[u] >> 28)], 1);
        }
    }
    __syncthreads();
    if (t == 0) {
        int s = 0;
#pragma unroll
        for (int i = 0; i < EPB; ++i) { basep[i] = s; s += cnt[i]; }
    }
    __syncthreads();
#pragma unroll
    for (int u = 0; u < CPT; ++u)
        if (rk[u] >= 0) se[basep[(int)(e[u] >> 28)] + rk[u]] = e[u];
    __syncthreads();

    const int novf = min(*ovfcnt, OVFCAP);     // 0 in practice

    // Phase B: 8 waves x 2 entities, jointly batched
    const int wv = t >> 6, lane = t & 63;
    const int loff = lane * 2;                 // _Float16 element offset in row

    const int leA = wv * 2, leB = leA + 1;
    const int s0A = basep[leA], cA = cnt[leA];
    const int s0B = basep[leB], cB = cnt[leB];
    float a0A = 0.f, a1A = 0.f, a0B = 0.f, a1B = 0.f;
    int jA = 0, jB = 0;
    while (jA + 8 <= cA && jB + 8 <= cB) {
        GATHER_BATCH8x2(s0A, jA, a0A, a1A, s0B, jB, a0B, a1B);
        jA += 8; jB += 8;
    }
    for (; jA + 8 <= cA; jA += 8) GATHER_BATCH8(s0A, jA, a0A, a1A);
    for (; jB + 8 <= cB; jB += 8) GATHER_BATCH8(s0B, jB, a0B, a1B);
    for (; jA < cA; ++jA) {
        const unsigned q = se[s0A + jA];
        const unsigned qs = __builtin_amdgcn_readfirstlane(q);
        const unsigned rwv = *reinterpret_cast<const unsigned*>(
            rwb + (size_t)((qs >> 16) & 0xFFFu) * 128 + loff);
        asm("v_fma_mix_f32 %[d], %[s0], %[s1], %[d] op_sel:[0,0,0] op_sel_hi:[1,1,0]"
            : [d]"+v"(a0A) : [s0]"s"(qs), [s1]"v"(rwv));
        asm("v_fma_mix_f32 %[d], %[s0], %[s1], %[d] op_sel:[0,1,0] op_sel_hi:[1,1,0]"
            : [d]"+v"(a1A) : [s0]"s"(qs), [s1]"v"(rwv));
    }
    for (; jB < cB; ++jB) {
        const unsigned q = se[s0B + jB];
        const unsigned qs = __builtin_amdgcn_readfirstlane(q);
        const unsigned rwv = *reinterpret_cast<const unsigned*>(
            rwb + (size_t)((qs >> 16) & 0xFFFu) * 128 + loff);
        asm("v_fma_mix_f32 %[d], %[s0], %[s1], %[d] op_sel:[0,0,0] op_sel_hi:[1,1,0]"
            : [d]"+v"(a0B) : [s0]"s"(qs), [s1]"v"(rwv));
        asm("v_fma_mix_f32 %[d], %[s0], %[s1], %[d] op_sel:[0,1,0] op_sel_hi:[1,1,0]"
            : [d]"+v"(a1B) : [s0]"s"(qs), [s1]"v"(rwv));
    }
    // exact overflow contributions (novf == 0 in practice)
    for (int k = 0; k < novf; ++k) {
        const uint2 o = ovf[k];
        if ((int)(o.x >> 16) == b) {
            const int ole = (int)((o.x >> 12) & 15u);
            if (ole == leA || ole == leB) {
                const int orel = (int)(o.x & 0xFFFu);
                const float ov = __uint_as_float(o.y);
                const unsigned orw = *reinterpret_cast<const unsigned*>(
                    rwb + (size_t)orel * 128 + loff);
                const half2v oh = __builtin_bit_cast(half2v, orw);
                if (ole == leA) { a0A += ov * (float)oh[0]; a1A += ov * (float)oh[1]; }
                else            { a0B += ov * (float)oh[0]; a1B += ov * (float)oh[1]; }
            }
        }
    }
    {
        const int ventA = b * EPB + leA;
        if (ventA < NUMENT) {
            float* op = out + (size_t)ventA * 128 + loff;
            float2 o2; o2.x = fmaxf(a0A, 0.f); o2.y = fmaxf(a1A, 0.f);
            *reinterpret_cast<float2*>(op) = o2;
        }
        const int ventB = b * EPB + leB;
        if (ventB < NUMENT) {
            float* op = out + (size_t)ventB * 128 + loff;
            float2 o2; o2.x = fmaxf(a0B, 0.f); o2.y = fmaxf(a1B, 0.f);
            *reinterpret_cast<float2*>(op) = o2;
        }
    }
}

// ---------------------------------------------------------------------------
// Fallback path (ws too small / shape out of range): direct vector scatter.
// ---------------------------------------------------------------------------
__global__ void rwb_f32_kernel(const float* __restrict__ rel, const float* __restrict__ W,
                               const float* __restrict__ b, float* __restrict__ rwb, int R) {
    const int k = blockIdx.x;
    const int n = threadIdx.x;
    __shared__ float relk[128];
    relk[n] = rel[(size_t)k * 128 + n];
    __syncthreads();
    const float4* w4 = reinterpret_cast<const float4*>(W + (size_t)n * 128);
    const float4* r4 = reinterpret_cast<const float4*>(relk);
    float acc = 0.f;
#pragma unroll
    for (int i = 0; i < 32; ++i) {
        float4 a = r4[i], w = w4[i];
        acc += a.x * w.x + a.y * w.y + a.z * w.z + a.w * w.w;
    }
    rwb[(size_t)k * 128 + n] = acc + b[n];
}

__global__ void scatter_vec_kernel(const int* __restrict__ heads, const int* __restrict__ tails,
                                   const int* __restrict__ rels, const float* __restrict__ val,
                                   const float* __restrict__ rwb, float* __restrict__ out,
                                   long long nitems) {
    const long long i = (long long)blockIdx.x * blockDim.x + threadIdx.x;
    if (i >= nitems) return;
    const int e = (int)(i >> 5);
    const int c = (int)(i & 31) * 4;
    const float v = val[e];
    float4 rw = *reinterpret_cast<const float4*>(rwb + (size_t)rels[e] * 128 + c);
    float* pt = out + (size_t)tails[e] * 128 + c;
    float* ph = out + (size_t)heads[e] * 128 + c;
    unsafeAtomicAdd(pt + 0, v * rw.x); unsafeAtomicAdd(pt + 1, v * rw.y);
    unsafeAtomicAdd(pt + 2, v * rw.z); unsafeAtomicAdd(pt + 3, v * rw.w);
    unsafeAtomicAdd(ph + 0, v * rw.x); unsafeAtomicAdd(ph + 1, v * rw.y);
    unsafeAtomicAdd(ph + 2, v * rw.z); unsafeAtomicAdd(ph + 3, v * rw.w);
}

__global__ void relu_kernel(float* __restrict__ out, int n4) {
    const int i = blockIdx.x * blockDim.x + threadIdx.x;
    if (i >= n4) return;
    float4* p = reinterpret_cast<float4*>(out) + i;
    float4 v = *p;
    v.x = fmaxf(v.x, 0.f); v.y = fmaxf(v.y, 0.f);
    v.z = fmaxf(v.z, 0.f); v.w = fmaxf(v.w, 0.f);
    *p = v;
}

// ---------------------------------------------------------------------------
extern "C" void kernel_launch(void* const* d_in, const int* in_sizes, int n_in,
                              void* d_out, int out_size, void* d_ws, size_t ws_size,
                              hipStream_t stream) {
    // inputs: 0 local_entity [B*M] (shape only), 1 heads [E], 2 tails [E],
    //         3 rels [E], 4 val [E], 5 rel_features [R*D], 6 W [D*D], 7 b [D]
    const int* heads = (const int*)d_in[1];
    const int* tails = (const int*)d_in[2];
    const int* rels  = (const int*)d_in[3];
    const float* val  = (const float*)d_in[4];
    const float* relf = (const float*)d_in[5];
    const float* W    = (const float*)d_in[6];
    const float* b    = (const float*)d_in[7];
    float* out = (float*)d_out;

    const int NUMENT = in_sizes[0];          // 16000
    const int E      = in_sizes[1];          // 2,000,000
    const int D      = in_sizes[7];          // 128
    const int R      = in_sizes[5] / D;      // 2000

    const int NB = (NUMENT + EPB - 1) / EPB; // 1000 buckets
    const int NBLK = (E + FPB - 1) / FPB;    // 245 bin blocks
    // padded per-bucket mean = real mean + NBLK * E[pad] (pad avg ~8, worst 15)
    const long long mean = (2LL * E * EPB) / (NUMENT > 0 ? NUMENT : 1);
    int CAPB = (int)(mean + (long long)NBLK * 9 + mean / 16 + 256);
    CAPB = (CAPB + GRAN - 1) & ~(GRAN - 1);

    // ws layout: rwb | ctrl { gcnt[NB], ovfcnt } | ovf[OVFCAP] | slots
    const size_t rwb_bytes = (size_t)R * D * sizeof(_Float16);          // 512 KB
    const size_t off_ctrl  = (rwb_bytes + 255) & ~(size_t)255;
    const size_t ctrl_b    = (size_t)(NB + 1) * sizeof(int);
    const size_t off_ovf   = (off_ctrl + ctrl_b + 255) & ~(size_t)255;
    const size_t ovf_b     = (size_t)OVFCAP * sizeof(uint2);            // 512 KB
    const size_t off_slots = (off_ovf + ovf_b + 255) & ~(size_t)255;
    const size_t slots_b   = (size_t)NB * CAPB * sizeof(unsigned);      // ~27 MB

    if (NB <= MAXNB && R < 4096 && CAPB <= SORTCAP &&
        ws_size >= off_slots + slots_b) {
        _Float16* rwb   = (_Float16*)d_ws;
        int* gcnt       = (int*)((char*)d_ws + off_ctrl);
        int* ovfcnt     = gcnt + NB;
        uint2* ovf      = (uint2*)((char*)d_ws + off_ovf);
        unsigned* slots = (unsigned*)((char*)d_ws + off_slots);

        hipMemsetAsync(gcnt, 0, ctrl_b, stream);     // gcnt + ovfcnt (4 KB)
        bin_rwb_kernel<<<NBLK, 1024, 0, stream>>>(
            heads, tails, rels, val, relf, W, b, rwb,
            gcnt, ovfcnt, ovf, slots, E, R, NB, CAPB);
        gather_kernel<<<NB, 512, 0, stream>>>(
            slots, gcnt, ovfcnt, ovf, rwb, out, NUMENT, CAPB);
    } else {
        // fallback: accumulate directly into out (slow but small-ws safe)
        float* rwb = (float*)d_ws;           // R*D fp32 (~1 MB)
        hipMemsetAsync(out, 0, (size_t)out_size * sizeof(float), stream);
        rwb_f32_kernel<<<R, 128, 0, stream>>>(relf, W, b, rwb, R);
        const long long items = (long long)E * 32;
        scatter_vec_kernel<<<(unsigned)((items + 255) / 256), 256, 0, stream>>>(
            heads, tails, rels, val, rwb, out, items);
        relu_kernel<<<(out_size / 4 + 255) / 256, 256, 0, stream>>>(out, out_size / 4);
    }
}

// Round 16
// 199.785 us; speedup vs baseline: 1.0291x; 1.0291x over previous
//
#include <hip/hip_runtime.h>
#include <hip/hip_bf16.h>
#include <cstdint>

typedef _Float16 half2v __attribute__((ext_vector_type(2)));

#define EPB   16        // entities per bucket
#define MAXNB 1024      // max buckets for bin LDS histogram (NUMENT <= 16384)
#define FPB   4096      // facts per bin-block (512 thr x FPT 8) -> 489 blocks
#define FPT   8         // facts per thread (CONSECUTIVE -> dwordx4 loads)
#define SORTCAP 4608    // gather LDS payload capacity (u32 -> 18 KB)
#define CPT   9         // ceil(SORTCAP / 512) register-held entries per thread
#define OVFCAP 65536    // overflow list capacity (512 KB; statistically unreachable)

// payload u32: [31:28]=local entity (4b) | [27:16]=rel (12b, R<4096) | [15:0]=fp16(val)
// overflow uint2: x = (bucket<<16) | (le<<12) | rel, y = fp32(val) bits

// ---------------------------------------------------------------------------
// Kernel 1: bin endpoints into per-bucket lists + appended RWB table build.
// r14 PMC: WRITE 71MB for 18.5MB payload — runs stored by 16 different
// threads at scattered TIMES -> lines evicted partially-dirty repeatedly.
// r15's pad fix backfired (pads = more scattered stores; 245-block grid).
// This version: counting-sort the block's payloads into LDS (32KB), then
// write each bucket run as ONE coalesced wave store — line fully assembled
// in a single op, ~16x fewer store instructions, exact reservations, no pads.
// ---------------------------------------------------------------------------
__global__ __launch_bounds__(512) void bin_rwb_kernel(
    const int* __restrict__ heads, const int* __restrict__ tails,
    const int* __restrict__ rels, const float* __restrict__ val,
    const float* __restrict__ relf, const float* __restrict__ W,
    const float* __restrict__ bias, _Float16* __restrict__ rwb,
    int* __restrict__ gcnt, int* __restrict__ ovfcnt, uint2* __restrict__ ovf,
    unsigned* __restrict__ slots,
    int E, int R, int NB, int CAPB) {
    __shared__ int cnt[MAXNB];          // 4 KB  per-block bucket counts
    __shared__ int gbase[MAXNB];        // 4 KB  global reservation base
    __shared__ int lbase[MAXNB];        // 4 KB  local sorted-array base
    __shared__ int wsum[8];
    __shared__ unsigned sse[2 * FPB];   // 32 KB sorted payloads
    const int t = threadIdx.x;
    for (int k = t; k < NB; k += 512) cnt[k] = 0;
    __syncthreads();

    // ---- phase 1: load facts, compute payloads, LDS rank ----
    const int i0 = blockIdx.x * FPB + t * FPT;
    unsigned payT[FPT], payH[FPT], prT[FPT], prH[FPT];
#pragma unroll
    for (int u = 0; u < FPT; ++u) { prT[u] = 0xFFFFFFFFu; prH[u] = 0xFFFFFFFFu; }

    int tl[FPT], hd[FPT], rr[FPT];
    float vv[FPT];
    int nval = 0;
    if (i0 + FPT <= E) {
        *reinterpret_cast<int4*>(&tl[0]) = *reinterpret_cast<const int4*>(tails + i0);
        *reinterpret_cast<int4*>(&tl[4]) = *reinterpret_cast<const int4*>(tails + i0 + 4);
        *reinterpret_cast<int4*>(&hd[0]) = *reinterpret_cast<const int4*>(heads + i0);
        *reinterpret_cast<int4*>(&hd[4]) = *reinterpret_cast<const int4*>(heads + i0 + 4);
        *reinterpret_cast<int4*>(&rr[0]) = *reinterpret_cast<const int4*>(rels + i0);
        *reinterpret_cast<int4*>(&rr[4]) = *reinterpret_cast<const int4*>(rels + i0 + 4);
        *reinterpret_cast<float4*>(&vv[0]) = *reinterpret_cast<const float4*>(val + i0);
        *reinterpret_cast<float4*>(&vv[4]) = *reinterpret_cast<const float4*>(val + i0 + 4);
        nval = FPT;
    } else {
#pragma unroll
        for (int u = 0; u < FPT; ++u) {
            const int i = i0 + u;
            if (i < E) {
                tl[u] = tails[i]; hd[u] = heads[i];
                rr[u] = rels[i];  vv[u] = val[i];
                nval = u + 1;
            }
        }
    }
#pragma unroll
    for (int u = 0; u < FPT; ++u) {
        if (u < nval) {
            const unsigned hv =
                (unsigned)__builtin_bit_cast(unsigned short, (_Float16)vv[u]);
            const int bt = tl[u] >> 4, bh = hd[u] >> 4;      // EPB = 16
            payT[u] = ((unsigned)(tl[u] & 15) << 28) | ((unsigned)rr[u] << 16) | hv;
            payH[u] = ((unsigned)(hd[u] & 15) << 28) | ((unsigned)rr[u] << 16) | hv;
            const int rt = atomicAdd(&cnt[bt], 1);           // LDS int rank (native)
            const int rh = atomicAdd(&cnt[bh], 1);
            prT[u] = ((unsigned)bt << 16) | (unsigned)rt;    // rank < 8192 fits
            prH[u] = ((unsigned)bh << 16) | (unsigned)rh;
        }
    }
    __syncthreads();

    // ---- phase 2a: block prefix scan of cnt -> lbase (pairs: 512 thr x 2) --
    {
        int c0 = (2 * t < NB) ? cnt[2 * t] : 0;
        int c1 = (2 * t + 1 < NB) ? cnt[2 * t + 1] : 0;
        const int pair = c0 + c1;
        int x = pair;
#pragma unroll
        for (int d = 1; d < 64; d <<= 1) {
            const int y = __shfl_up(x, d);
            if ((t & 63) >= d) x += y;
        }
        if ((t & 63) == 63) wsum[t >> 6] = x;
        __syncthreads();
        if (t < 64) {
            int v = (t < 8) ? wsum[t] : 0;
#pragma unroll
            for (int d = 1; d < 8; d <<= 1) {
                const int y = __shfl_up(v, d);
                if (t >= d) v += y;
            }
            if (t < 8) wsum[t] = v;              // inclusive wave sums
        }
        __syncthreads();
        const int woff = (t >= 64) ? wsum[(t >> 6) - 1] : 0;
        const int excl = x + woff - pair;        // exclusive scan of pairs
        if (2 * t < NB)     lbase[2 * t] = excl;
        if (2 * t + 1 < NB) lbase[2 * t + 1] = excl + c0;
    }
    // ---- phase 2b: global reservations (exact, no padding) ----
    for (int k = t; k < NB; k += 512) {
        const int c = cnt[k];
        gbase[k] = c ? atomicAdd(&gcnt[k], c) : 0;           // 1 atomic/bucket/block
    }
    __syncthreads();

    // ---- phase 3: place payloads into LDS sorted array ----
#pragma unroll
    for (int u = 0; u < FPT; ++u) {
        if (prT[u] != 0xFFFFFFFFu) {
            sse[lbase[(int)(prT[u] >> 16)] + (int)(prT[u] & 0xFFFFu)] = payT[u];
            sse[lbase[(int)(prH[u] >> 16)] + (int)(prH[u] & 0xFFFFu)] = payH[u];
        }
    }
    __syncthreads();

    // ---- phase 4: per-bucket coalesced run writeout (wave per bucket) ----
    const int wv = t >> 6, lane = t & 63;
    for (int k = wv; k < NB; k += 8) {
        const int len = cnt[k];
        const int lb  = lbase[k];
        const int gb  = gbase[k];
        for (int off = lane; off < len; off += 64) {
            const unsigned p = sse[lb + off];
            const int pos = gb + off;
            if (pos < CAPB) slots[(size_t)k * CAPB + pos] = p;
            else {
                const int op = atomicAdd(ovfcnt, 1);
                if (op < OVFCAP) {
                    uint2 o;
                    o.x = ((unsigned)k << 16) | ((p >> 28) << 12) | ((p >> 16) & 0xFFFu);
                    o.y = __float_as_uint(
                        (float)__builtin_bit_cast(_Float16, (unsigned short)(p & 0xFFFFu)));
                    ovf[op] = o;
                }
            }
        }
    }

    // ---- appended: RWB table (grid-strided, 4 rows / block-iteration) ----
    const int rsub = t >> 7;            // 0..3
    const int col  = t & 127;
    for (int row0 = blockIdx.x * 4; row0 < R; row0 += gridDim.x * 4) {
        const int row = row0 + rsub;
        if (row < R) {
            const float4* rp = reinterpret_cast<const float4*>(relf + (size_t)row * 128);
            const float4* wp = reinterpret_cast<const float4*>(W + (size_t)col * 128);
            float acc = 0.f;
#pragma unroll
            for (int i = 0; i < 32; ++i) {
                float4 a = rp[i], w = wp[i];
                acc += a.x * w.x + a.y * w.y + a.z * w.z + a.w * w.w;
            }
            rwb[(size_t)row * 128 + col] = (_Float16)(acc + bias[col]);
        }
    }
}

// batch-of-8 for one entity: named registers, no rotation copies
#define GATHER_BATCH8(S0, J, A0, A1)                                            \
    {                                                                           \
        uint2 qp[4];                                                            \
        _Pragma("unroll")                                                       \
        for (int u = 0; u < 4; ++u)                                             \
            qp[u] = *reinterpret_cast<const uint2*>(&se[(S0) + (J) + 2 * u]);   \
        unsigned qs[8];                                                         \
        _Pragma("unroll")                                                       \
        for (int u = 0; u < 4; ++u) {                                           \
            qs[2 * u]     = __builtin_amdgcn_readfirstlane(qp[u].x);            \
            qs[2 * u + 1] = __builtin_amdgcn_readfirstlane(qp[u].y);            \
        }                                                                       \
        unsigned rw[8];                                                         \
        _Pragma("unroll")                                                       \
        for (int u = 0; u < 8; ++u) {                                           \
            const _Float16* rowp = rwb + (size_t)((qs[u] >> 16) & 0xFFFu) * 128;\
            rw[u] = *reinterpret_cast<const unsigned*>(rowp + loff);            \
        }                                                                       \
        _Pragma("unroll")                                                       \
        for (int u = 0; u < 8; ++u) {                                           \
            asm("v_fma_mix_f32 %[d], %[s0], %[s1], %[d] op_sel:[0,0,0] op_sel_hi:[1,1,0]" \
                : [d]"+v"(A0) : [s0]"s"(qs[u]), [s1]"v"(rw[u]));                \
            asm("v_fma_mix_f32 %[d], %[s0], %[s1], %[d] op_sel:[0,1,0] op_sel_hi:[1,1,0]" \
                : [d]"+v"(A1) : [s0]"s"(qs[u]), [s1]"v"(rw[u]));                \
        }                                                                       \
    }

// joint batch: both entities' loads issued before either's FMAs -> 2 chains
#define GATHER_BATCH8x2(S0A, JA, A0A, A1A, S0B, JB, A0B, A1B)                   \
    {                                                                           \
        uint2 qpa[4], qpb[4];                                                   \
        _Pragma("unroll")                                                       \
        for (int u = 0; u < 4; ++u) {                                           \
            qpa[u] = *reinterpret_cast<const uint2*>(&se[(S0A) + (JA) + 2 * u]);\
            qpb[u] = *reinterpret_cast<const uint2*>(&se[(S0B) + (JB) + 2 * u]);\
        }                                                                       \
        unsigned qsa[8], qsb[8];                                                \
        _Pragma("unroll")                                                       \
        for (int u = 0; u < 4; ++u) {                                           \
            qsa[2 * u]     = __builtin_amdgcn_readfirstlane(qpa[u].x);          \
            qsa[2 * u + 1] = __builtin_amdgcn_readfirstlane(qpa[u].y);          \
            qsb[2 * u]     = __builtin_amdgcn_readfirstlane(qpb[u].x);          \
            qsb[2 * u + 1] = __builtin_amdgcn_readfirstlane(qpb[u].y);          \
        }                                                                       \
        unsigned rwa[8], rwb_[8];                                               \
        _Pragma("unroll")                                                       \
        for (int u = 0; u < 8; ++u) {                                           \
            rwa[u] = *reinterpret_cast<const unsigned*>(                        \
                rwb + (size_t)((qsa[u] >> 16) & 0xFFFu) * 128 + loff);          \
            rwb_[u] = *reinterpret_cast<const unsigned*>(                       \
                rwb + (size_t)((qsb[u] >> 16) & 0xFFFu) * 128 + loff);          \
        }                                                                       \
        _Pragma("unroll")                                                       \
        for (int u = 0; u < 8; ++u) {                                           \
            asm("v_fma_mix_f32 %[d], %[s0], %[s1], %[d] op_sel:[0,0,0] op_sel_hi:[1,1,0]" \
                : [d]"+v"(A0A) : [s0]"s"(qsa[u]), [s1]"v"(rwa[u]));             \
            asm("v_fma_mix_f32 %[d], %[s0], %[s1], %[d] op_sel:[0,1,0] op_sel_hi:[1,1,0]" \
                : [d]"+v"(A1A) : [s0]"s"(qsa[u]), [s1]"v"(rwa[u]));             \
            asm("v_fma_mix_f32 %[d], %[s0], %[s1], %[d] op_sel:[0,0,0] op_sel_hi:[1,1,0]" \
                : [d]"+v"(A0B) : [s0]"s"(qsb[u]), [s1]"v"(rwb_[u]));            \
            asm("v_fma_mix_f32 %[d], %[s0], %[s1], %[d] op_sel:[0,1,0] op_sel_hi:[1,1,0]" \
                : [d]"+v"(A1B) : [s0]"s"(qsb[u]), [s1]"v"(rwb_[u]));            \
        }                                                                       \
    }

// ---------------------------------------------------------------------------
// Kernel 2: gather — one 512-thread block per 16-entity bucket.
// EXACT r14 kernel (proven best): Phase A counting sort into 18KB LDS,
// Phase B joint-batched dual-entity scalarized loop.
// ---------------------------------------------------------------------------
__global__ __launch_bounds__(512) void gather_kernel(
    const unsigned* __restrict__ slots, const int* __restrict__ gcnt,
    const int* __restrict__ ovfcnt, const uint2* __restrict__ ovf,
    const _Float16* __restrict__ rwb, float* __restrict__ out,
    int NUMENT, int CAPB) {
    __shared__ unsigned se[SORTCAP];           // 18 KB sorted payloads
    __shared__ int cnt[EPB], basep[EPB];
    const int t = threadIdx.x;
    const int b = blockIdx.x;
    if (t < EPB) cnt[t] = 0;
    __syncthreads();

    int deg = gcnt[b];
    if (deg > CAPB) deg = CAPB;        // overflow entries went to ovf list
    const unsigned* sl = slots + (size_t)b * CAPB;

    // Phase A: coalesced load, LDS rank, hold in registers, sorted placement
    unsigned e[CPT];
    int rk[CPT];
#pragma unroll
    for (int u = 0; u < CPT; ++u) {
        const int k = t + u * 512;
        rk[u] = -1;
        if (k < deg) {
            e[u] = sl[k];
            rk[u] = atomicAdd(&cnt[(int)(e[u] >> 28)], 1);
        }
    }
    __syncthreads();
    if (t == 0) {
        int s = 0;
#pragma unroll
        for (int i = 0; i < EPB; ++i) { basep[i] = s; s += cnt[i]; }
    }
    __syncthreads();
#pragma unroll
    for (int u = 0; u < CPT; ++u)
        if (rk[u] >= 0) se[basep[(int)(e[u] >> 28)] + rk[u]] = e[u];
    __syncthreads();

    const int novf = min(*ovfcnt, OVFCAP);     // 0 in practice

    // Phase B: 8 waves x 2 entities, jointly batched
    const int wv = t >> 6, lane = t & 63;
    const int loff = lane * 2;                 // _Float16 element offset in row

    const int leA = wv * 2, leB = leA + 1;
    const int s0A = basep[leA], cA = cnt[leA];
    const int s0B = basep[leB], cB = cnt[leB];
    float a0A = 0.f, a1A = 0.f, a0B = 0.f, a1B = 0.f;
    int jA = 0, jB = 0;
    while (jA + 8 <= cA && jB + 8 <= cB) {
        GATHER_BATCH8x2(s0A, jA, a0A, a1A, s0B, jB, a0B, a1B);
        jA += 8; jB += 8;
    }
    for (; jA + 8 <= cA; jA += 8) GATHER_BATCH8(s0A, jA, a0A, a1A);
    for (; jB + 8 <= cB; jB += 8) GATHER_BATCH8(s0B, jB, a0B, a1B);
    for (; jA < cA; ++jA) {
        const unsigned q = se[s0A + jA];
        const unsigned qs = __builtin_amdgcn_readfirstlane(q);
        const unsigned rwv = *reinterpret_cast<const unsigned*>(
            rwb + (size_t)((qs >> 16) & 0xFFFu) * 128 + loff);
        asm("v_fma_mix_f32 %[d], %[s0], %[s1], %[d] op_sel:[0,0,0] op_sel_hi:[1,1,0]"
            : [d]"+v"(a0A) : [s0]"s"(qs), [s1]"v"(rwv));
        asm("v_fma_mix_f32 %[d], %[s0], %[s1], %[d] op_sel:[0,1,0] op_sel_hi:[1,1,0]"
            : [d]"+v"(a1A) : [s0]"s"(qs), [s1]"v"(rwv));
    }
    for (; jB < cB; ++jB) {
        const unsigned q = se[s0B + jB];
        const unsigned qs = __builtin_amdgcn_readfirstlane(q);
        const unsigned rwv = *reinterpret_cast<const unsigned*>(
            rwb + (size_t)((qs >> 16) & 0xFFFu) * 128 + loff);
        asm("v_fma_mix_f32 %[d], %[s0], %[s1], %[d] op_sel:[0,0,0] op_sel_hi:[1,1,0]"
            : [d]"+v"(a0B) : [s0]"s"(qs), [s1]"v"(rwv));
        asm("v_fma_mix_f32 %[d], %[s0], %[s1], %[d] op_sel:[0,1,0] op_sel_hi:[1,1,0]"
            : [d]"+v"(a1B) : [s0]"s"(qs), [s1]"v"(rwv));
    }
    // exact overflow contributions (novf == 0 in practice)
    for (int k = 0; k < novf; ++k) {
        const uint2 o = ovf[k];
        if ((int)(o.x >> 16) == b) {
            const int ole = (int)((o.x >> 12) & 15u);
            if (ole == leA || ole == leB) {
                const int orel = (int)(o.x & 0xFFFu);
                const float ov = __uint_as_float(o.y);
                const unsigned orw = *reinterpret_cast<const unsigned*>(
                    rwb + (size_t)orel * 128 + loff);
                const half2v oh = __builtin_bit_cast(half2v, orw);
                if (ole == leA) { a0A += ov * (float)oh[0]; a1A += ov * (float)oh[1]; }
                else            { a0B += ov * (float)oh[0]; a1B += ov * (float)oh[1]; }
            }
        }
    }
    {
        const int ventA = b * EPB + leA;
        if (ventA < NUMENT) {
            float* op = out + (size_t)ventA * 128 + loff;
            float2 o2; o2.x = fmaxf(a0A, 0.f); o2.y = fmaxf(a1A, 0.f);
            *reinterpret_cast<float2*>(op) = o2;
        }
        const int ventB = b * EPB + leB;
        if (ventB < NUMENT) {
            float* op = out + (size_t)ventB * 128 + loff;
            float2 o2; o2.x = fmaxf(a0B, 0.f); o2.y = fmaxf(a1B, 0.f);
            *reinterpret_cast<float2*>(op) = o2;
        }
    }
}

// ---------------------------------------------------------------------------
// Fallback path (ws too small / shape out of range): direct vector scatter.
// ---------------------------------------------------------------------------
__global__ void rwb_f32_kernel(const float* __restrict__ rel, const float* __restrict__ W,
                               const float* __restrict__ b, float* __restrict__ rwb, int R) {
    const int k = blockIdx.x;
    const int n = threadIdx.x;
    __shared__ float relk[128];
    relk[n] = rel[(size_t)k * 128 + n];
    __syncthreads();
    const float4* w4 = reinterpret_cast<const float4*>(W + (size_t)n * 128);
    const float4* r4 = reinterpret_cast<const float4*>(relk);
    float acc = 0.f;
#pragma unroll
    for (int i = 0; i < 32; ++i) {
        float4 a = r4[i], w = w4[i];
        acc += a.x * w.x + a.y * w.y + a.z * w.z + a.w * w.w;
    }
    rwb[(size_t)k * 128 + n] = acc + b[n];
}

__global__ void scatter_vec_kernel(const int* __restrict__ heads, const int* __restrict__ tails,
                                   const int* __restrict__ rels, const float* __restrict__ val,
                                   const float* __restrict__ rwb, float* __restrict__ out,
                                   long long nitems) {
    const long long i = (long long)blockIdx.x * blockDim.x + threadIdx.x;
    if (i >= nitems) return;
    const int e = (int)(i >> 5);
    const int c = (int)(i & 31) * 4;
    const float v = val[e];
    float4 rw = *reinterpret_cast<const float4*>(rwb + (size_t)rels[e] * 128 + c);
    float* pt = out + (size_t)tails[e] * 128 + c;
    float* ph = out + (size_t)heads[e] * 128 + c;
    unsafeAtomicAdd(pt + 0, v * rw.x); unsafeAtomicAdd(pt + 1, v * rw.y);
    unsafeAtomicAdd(pt + 2, v * rw.z); unsafeAtomicAdd(pt + 3, v * rw.w);
    unsafeAtomicAdd(ph + 0, v * rw.x); unsafeAtomicAdd(ph + 1, v * rw.y);
    unsafeAtomicAdd(ph + 2, v * rw.z); unsafeAtomicAdd(ph + 3, v * rw.w);
}

__global__ void relu_kernel(float* __restrict__ out, int n4) {
    const int i = blockIdx.x * blockDim.x + threadIdx.x;
    if (i >= n4) return;
    float4* p = reinterpret_cast<float4*>(out) + i;
    float4 v = *p;
    v.x = fmaxf(v.x, 0.f); v.y = fmaxf(v.y, 0.f);
    v.z = fmaxf(v.z, 0.f); v.w = fmaxf(v.w, 0.f);
    *p = v;
}

// ---------------------------------------------------------------------------
extern "C" void kernel_launch(void* const* d_in, const int* in_sizes, int n_in,
                              void* d_out, int out_size, void* d_ws, size_t ws_size,
                              hipStream_t stream) {
    // inputs: 0 local_entity [B*M] (shape only), 1 heads [E], 2 tails [E],
    //         3 rels [E], 4 val [E], 5 rel_features [R*D], 6 W [D*D], 7 b [D]
    const int* heads = (const int*)d_in[1];
    const int* tails = (const int*)d_in[2];
    const int* rels  = (const int*)d_in[3];
    const float* val  = (const float*)d_in[4];
    const float* relf = (const float*)d_in[5];
    const float* W    = (const float*)d_in[6];
    const float* b    = (const float*)d_in[7];
    float* out = (float*)d_out;

    const int NUMENT = in_sizes[0];          // 16000
    const int E      = in_sizes[1];          // 2,000,000
    const int D      = in_sizes[7];          // 128
    const int R      = in_sizes[5] / D;      // 2000

    const int NB = (NUMENT + EPB - 1) / EPB; // 1000 buckets
    // expected endpoints/bucket = 2E*EPB/NUMENT (=4000, sigma~63);
    // slack mean/16+256 ~ +9.6 sigma at default shape
    const long long mean = (2LL * E * EPB) / (NUMENT > 0 ? NUMENT : 1);
    int CAPB = (int)(mean + mean / 16 + 256);

    // ws layout: rwb | ctrl { gcnt[NB], ovfcnt } | ovf[OVFCAP] | slots
    const size_t rwb_bytes = (size_t)R * D * sizeof(_Float16);          // 512 KB
    const size_t off_ctrl  = (rwb_bytes + 255) & ~(size_t)255;
    const size_t ctrl_b    = (size_t)(NB + 1) * sizeof(int);
    const size_t off_ovf   = (off_ctrl + ctrl_b + 255) & ~(size_t)255;
    const size_t ovf_b     = (size_t)OVFCAP * sizeof(uint2);            // 512 KB
    const size_t off_slots = (off_ovf + ovf_b + 255) & ~(size_t)255;
    const size_t slots_b   = (size_t)NB * CAPB * sizeof(unsigned);      // ~18 MB

    if (NB <= MAXNB && R < 4096 && CAPB <= SORTCAP &&
        ws_size >= off_slots + slots_b) {
        _Float16* rwb   = (_Float16*)d_ws;
        int* gcnt       = (int*)((char*)d_ws + off_ctrl);
        int* ovfcnt     = gcnt + NB;
        uint2* ovf      = (uint2*)((char*)d_ws + off_ovf);
        unsigned* slots = (unsigned*)((char*)d_ws + off_slots);

        hipMemsetAsync(gcnt, 0, ctrl_b, stream);     // gcnt + ovfcnt (4 KB)
        bin_rwb_kernel<<<(E + FPB - 1) / FPB, 512, 0, stream>>>(
            heads, tails, rels, val, relf, W, b, rwb,
            gcnt, ovfcnt, ovf, slots, E, R, NB, CAPB);
        gather_kernel<<<NB, 512, 0, stream>>>(
            slots, gcnt, ovfcnt, ovf, rwb, out, NUMENT, CAPB);
    } else {
        // fallback: accumulate directly into out (slow but small-ws safe)
        float* rwb = (float*)d_ws;           // R*D fp32 (~1 MB)
        hipMemsetAsync(out, 0, (size_t)out_size * sizeof(float), stream);
        rwb_f32_kernel<<<R, 128, 0, stream>>>(relf, W, b, rwb, R);
        const long long items = (long long)E * 32;
        scatter_vec_kernel<<<(unsigned)((items + 255) / 256), 256, 0, stream>>>(
            heads, tails, rels, val, rwb, out, items);
        relu_kernel<<<(out_size / 4 + 255) / 256, 256, 0, stream>>>(out, out_size / 4);
    }
}

// Round 17
// 185.470 us; speedup vs baseline: 1.1085x; 1.0772x over previous
//
#include <hip/hip_runtime.h>
#include <hip/hip_bf16.h>
#include <cstdint>

typedef _Float16 half2v __attribute__((ext_vector_type(2)));

#define EPB   16        // entities per bucket
#define MAXNB 1024      // max buckets for bin LDS histogram (NUMENT <= 16384)
#define FPB   4096      // facts per bin-block (1024 thr x FPT 4) -> 489 blocks
#define FPT   4         // facts per thread (CONSECUTIVE -> dwordx4 loads)
#define SORTCAP 4608    // gather LDS payload capacity (u32 -> 18 KB)
#define CPT   9         // ceil(SORTCAP / 512) register-held entries per thread
#define OVFCAP 65536    // overflow list capacity (512 KB; statistically unreachable)

// payload u32: [31:28]=local entity (4b) | [27:16]=rel (12b, R<4096) | [15:0]=fp16(val)
// overflow uint2: x = (bucket<<16) | (le<<12) | rel, y = fp32(val) bits

// ---------------------------------------------------------------------------
// Kernel 1: bin endpoints into per-bucket lists + appended RWB table build.
// PROVEN BEST (r13/r14 bench: 186.1us total, bin 58.8us). r15 (sector pads)
// and r16 (LDS-sort coalesced writeout) both regressed: bin is latency-bound
// on the scattered-store path, NOT write-BW-bound (r16: WRITE 71->29MB yet
// 59->71us). Direct scattered stores + max occupancy is the bracketed floor.
// ---------------------------------------------------------------------------
__global__ __launch_bounds__(1024) void bin_rwb_kernel(
    const int* __restrict__ heads, const int* __restrict__ tails,
    const int* __restrict__ rels, const float* __restrict__ val,
    const float* __restrict__ relf, const float* __restrict__ W,
    const float* __restrict__ bias, _Float16* __restrict__ rwb,
    int* __restrict__ gcnt, int* __restrict__ ovfcnt, uint2* __restrict__ ovf,
    unsigned* __restrict__ slots,
    int E, int R, int NB, int CAPB) {
    __shared__ int cnt[MAXNB];
    __shared__ int gbase[MAXNB];
    const int t = threadIdx.x;
    for (int k = t; k < NB; k += 1024) cnt[k] = 0;
    __syncthreads();

    const int i0 = blockIdx.x * FPB + t * FPT;
    unsigned payT[FPT], payH[FPT], prT[FPT], prH[FPT];
#pragma unroll
    for (int u = 0; u < FPT; ++u) { prT[u] = 0xFFFFFFFFu; prH[u] = 0xFFFFFFFFu; }

    int tl[FPT], hd[FPT], rr[FPT];
    float vv[FPT];
    int nval = 0;
    if (i0 + FPT <= E) {
        const int4 T  = *reinterpret_cast<const int4*>(tails + i0);
        const int4 H  = *reinterpret_cast<const int4*>(heads + i0);
        const int4 Rv = *reinterpret_cast<const int4*>(rels + i0);
        const float4 Vv = *reinterpret_cast<const float4*>(val + i0);
        tl[0] = T.x;  tl[1] = T.y;  tl[2] = T.z;  tl[3] = T.w;
        hd[0] = H.x;  hd[1] = H.y;  hd[2] = H.z;  hd[3] = H.w;
        rr[0] = Rv.x; rr[1] = Rv.y; rr[2] = Rv.z; rr[3] = Rv.w;
        vv[0] = Vv.x; vv[1] = Vv.y; vv[2] = Vv.z; vv[3] = Vv.w;
        nval = FPT;
    } else {
#pragma unroll
        for (int u = 0; u < FPT; ++u) {
            const int i = i0 + u;
            if (i < E) {
                tl[u] = tails[i]; hd[u] = heads[i];
                rr[u] = rels[i];  vv[u] = val[i];
                nval = u + 1;
            }
        }
    }
#pragma unroll
    for (int u = 0; u < FPT; ++u) {
        if (u < nval) {
            const unsigned hv =
                (unsigned)__builtin_bit_cast(unsigned short, (_Float16)vv[u]);
            const int bt = tl[u] >> 4, bh = hd[u] >> 4;      // EPB = 16
            payT[u] = ((unsigned)(tl[u] & 15) << 28) | ((unsigned)rr[u] << 16) | hv;
            payH[u] = ((unsigned)(hd[u] & 15) << 28) | ((unsigned)rr[u] << 16) | hv;
            const int rt = atomicAdd(&cnt[bt], 1);           // LDS int rank (native)
            const int rh = atomicAdd(&cnt[bh], 1);
            prT[u] = ((unsigned)bt << 16) | (unsigned)rt;    // rank < 16384 fits
            prH[u] = ((unsigned)bh << 16) | (unsigned)rh;
        }
    }
    __syncthreads();
    for (int k = t; k < NB; k += 1024) {
        const int c = cnt[k];
        gbase[k] = c ? atomicAdd(&gcnt[k], c) : 0;           // 1 atomic / bucket / block
    }
    __syncthreads();
#pragma unroll
    for (int u = 0; u < FPT; ++u) {
        if (prT[u] != 0xFFFFFFFFu) {
            {
                const int b1 = (int)(prT[u] >> 16);
                const int pos = gbase[b1] + (int)(prT[u] & 0xFFFFu);
                if (pos < CAPB) slots[(size_t)b1 * CAPB + pos] = payT[u];
                else {
                    const int op = atomicAdd(ovfcnt, 1);
                    if (op < OVFCAP) {
                        uint2 o;
                        o.x = ((unsigned)b1 << 16) | ((payT[u] >> 28) << 12) |
                              ((payT[u] >> 16) & 0xFFFu);
                        o.y = __float_as_uint(vv[u]);
                        ovf[op] = o;
                    }
                }
            }
            {
                const int b1 = (int)(prH[u] >> 16);
                const int pos = gbase[b1] + (int)(prH[u] & 0xFFFFu);
                if (pos < CAPB) slots[(size_t)b1 * CAPB + pos] = payH[u];
                else {
                    const int op = atomicAdd(ovfcnt, 1);
                    if (op < OVFCAP) {
                        uint2 o;
                        o.x = ((unsigned)b1 << 16) | ((payH[u] >> 28) << 12) |
                              ((payH[u] >> 16) & 0xFFFu);
                        o.y = __float_as_uint(vv[u]);
                        ovf[op] = o;
                    }
                }
            }
        }
    }

    // ---- appended: RWB table (grid-strided, 8 rows / block-iteration) ----
    const int rsub = t >> 7;            // 0..7
    const int col  = t & 127;
    for (int row0 = blockIdx.x * 8; row0 < R; row0 += gridDim.x * 8) {
        const int row = row0 + rsub;
        if (row < R) {
            const float4* rp = reinterpret_cast<const float4*>(relf + (size_t)row * 128);
            const float4* wp = reinterpret_cast<const float4*>(W + (size_t)col * 128);
            float acc = 0.f;
#pragma unroll
            for (int i = 0; i < 32; ++i) {
                float4 a = rp[i], w = wp[i];
                acc += a.x * w.x + a.y * w.y + a.z * w.z + a.w * w.w;
            }
            rwb[(size_t)row * 128 + col] = (_Float16)(acc + bias[col]);
        }
    }
}

// batch-of-8 for one entity: named registers, no rotation copies
#define GATHER_BATCH8(S0, J, A0, A1)                                            \
    {                                                                           \
        uint2 qp[4];                                                            \
        _Pragma("unroll")                                                       \
        for (int u = 0; u < 4; ++u)                                             \
            qp[u] = *reinterpret_cast<const uint2*>(&se[(S0) + (J) + 2 * u]);   \
        unsigned qs[8];                                                         \
        _Pragma("unroll")                                                       \
        for (int u = 0; u < 4; ++u) {                                           \
            qs[2 * u]     = __builtin_amdgcn_readfirstlane(qp[u].x);            \
            qs[2 * u + 1] = __builtin_amdgcn_readfirstlane(qp[u].y);            \
        }                                                                       \
        unsigned rw[8];                                                         \
        _Pragma("unroll")                                                       \
        for (int u = 0; u < 8; ++u) {                                           \
            const _Float16* rowp = rwb + (size_t)((qs[u] >> 16) & 0xFFFu) * 128;\
            rw[u] = *reinterpret_cast<const unsigned*>(rowp + loff);            \
        }                                                                       \
        _Pragma("unroll")                                                       \
        for (int u = 0; u < 8; ++u) {                                           \
            asm("v_fma_mix_f32 %[d], %[s0], %[s1], %[d] op_sel:[0,0,0] op_sel_hi:[1,1,0]" \
                : [d]"+v"(A0) : [s0]"s"(qs[u]), [s1]"v"(rw[u]));                \
            asm("v_fma_mix_f32 %[d], %[s0], %[s1], %[d] op_sel:[0,1,0] op_sel_hi:[1,1,0]" \
                : [d]"+v"(A1) : [s0]"s"(qs[u]), [s1]"v"(rw[u]));                \
        }                                                                       \
    }

// joint batch: both entities' loads issued before either's FMAs -> 2 chains
#define GATHER_BATCH8x2(S0A, JA, A0A, A1A, S0B, JB, A0B, A1B)                   \
    {                                                                           \
        uint2 qpa[4], qpb[4];                                                   \
        _Pragma("unroll")                                                       \
        for (int u = 0; u < 4; ++u) {                                           \
            qpa[u] = *reinterpret_cast<const uint2*>(&se[(S0A) + (JA) + 2 * u]);\
            qpb[u] = *reinterpret_cast<const uint2*>(&se[(S0B) + (JB) + 2 * u]);\
        }                                                                       \
        unsigned qsa[8], qsb[8];                                                \
        _Pragma("unroll")                                                       \
        for (int u = 0; u < 4; ++u) {                                           \
            qsa[2 * u]     = __builtin_amdgcn_readfirstlane(qpa[u].x);          \
            qsa[2 * u + 1] = __builtin_amdgcn_readfirstlane(qpa[u].y);          \
            qsb[2 * u]     = __builtin_amdgcn_readfirstlane(qpb[u].x);          \
            qsb[2 * u + 1] = __builtin_amdgcn_readfirstlane(qpb[u].y);          \
        }                                                                       \
        unsigned rwa[8], rwb_[8];                                               \
        _Pragma("unroll")                                                       \
        for (int u = 0; u < 8; ++u) {                                           \
            rwa[u] = *reinterpret_cast<const unsigned*>(                        \
                rwb + (size_t)((qsa[u] >> 16) & 0xFFFu) * 128 + loff);          \
            rwb_[u] = *reinterpret_cast<const unsigned*>(                       \
                rwb + (size_t)((qsb[u] >> 16) & 0xFFFu) * 128 + loff);          \
        }                                                                       \
        _Pragma("unroll")                                                       \
        for (int u = 0; u < 8; ++u) {                                           \
            asm("v_fma_mix_f32 %[d], %[s0], %[s1], %[d] op_sel:[0,0,0] op_sel_hi:[1,1,0]" \
                : [d]"+v"(A0A) : [s0]"s"(qsa[u]), [s1]"v"(rwa[u]));             \
            asm("v_fma_mix_f32 %[d], %[s0], %[s1], %[d] op_sel:[0,1,0] op_sel_hi:[1,1,0]" \
                : [d]"+v"(A1A) : [s0]"s"(qsa[u]), [s1]"v"(rwa[u]));             \
            asm("v_fma_mix_f32 %[d], %[s0], %[s1], %[d] op_sel:[0,0,0] op_sel_hi:[1,1,0]" \
                : [d]"+v"(A0B) : [s0]"s"(qsb[u]), [s1]"v"(rwb_[u]));            \
            asm("v_fma_mix_f32 %[d], %[s0], %[s1], %[d] op_sel:[0,1,0] op_sel_hi:[1,1,0]" \
                : [d]"+v"(A1B) : [s0]"s"(qsb[u]), [s1]"v"(rwb_[u]));            \
        }                                                                       \
    }

// ---------------------------------------------------------------------------
// Kernel 2: gather — one 512-thread block per 16-entity bucket.
// PROVEN BEST (r13/r14): Phase A counting sort into 18KB LDS, Phase B
// joint-batched dual-entity scalarized loop (2 dependence chains in flight).
// ---------------------------------------------------------------------------
__global__ __launch_bounds__(512) void gather_kernel(
    const unsigned* __restrict__ slots, const int* __restrict__ gcnt,
    const int* __restrict__ ovfcnt, const uint2* __restrict__ ovf,
    const _Float16* __restrict__ rwb, float* __restrict__ out,
    int NUMENT, int CAPB) {
    __shared__ unsigned se[SORTCAP];           // 18 KB sorted payloads
    __shared__ int cnt[EPB], basep[EPB];
    const int t = threadIdx.x;
    const int b = blockIdx.x;
    if (t < EPB) cnt[t] = 0;
    __syncthreads();

    int deg = gcnt[b];
    if (deg > CAPB) deg = CAPB;        // overflow entries went to ovf list
    const unsigned* sl = slots + (size_t)b * CAPB;

    // Phase A: coalesced load, LDS rank, hold in registers, sorted placement
    unsigned e[CPT];
    int rk[CPT];
#pragma unroll
    for (int u = 0; u < CPT; ++u) {
        const int k = t + u * 512;
        rk[u] = -1;
        if (k < deg) {
            e[u] = sl[k];
            rk[u] = atomicAdd(&cnt[(int)(e[u] >> 28)], 1);
        }
    }
    __syncthreads();
    if (t == 0) {
        int s = 0;
#pragma unroll
        for (int i = 0; i < EPB; ++i) { basep[i] = s; s += cnt[i]; }
    }
    __syncthreads();
#pragma unroll
    for (int u = 0; u < CPT; ++u)
        if (rk[u] >= 0) se[basep[(int)(e[u] >> 28)] + rk[u]] = e[u];
    __syncthreads();

    const int novf = min(*ovfcnt, OVFCAP);     // 0 in practice

    // Phase B: 8 waves x 2 entities, jointly batched
    const int wv = t >> 6, lane = t & 63;
    const int loff = lane * 2;                 // _Float16 element offset in row

    const int leA = wv * 2, leB = leA + 1;
    const int s0A = basep[leA], cA = cnt[leA];
    const int s0B = basep[leB], cB = cnt[leB];
    float a0A = 0.f, a1A = 0.f, a0B = 0.f, a1B = 0.f;
    int jA = 0, jB = 0;
    while (jA + 8 <= cA && jB + 8 <= cB) {
        GATHER_BATCH8x2(s0A, jA, a0A, a1A, s0B, jB, a0B, a1B);
        jA += 8; jB += 8;
    }
    for (; jA + 8 <= cA; jA += 8) GATHER_BATCH8(s0A, jA, a0A, a1A);
    for (; jB + 8 <= cB; jB += 8) GATHER_BATCH8(s0B, jB, a0B, a1B);
    for (; jA < cA; ++jA) {
        const unsigned q = se[s0A + jA];
        const unsigned qs = __builtin_amdgcn_readfirstlane(q);
        const unsigned rwv = *reinterpret_cast<const unsigned*>(
            rwb + (size_t)((qs >> 16) & 0xFFFu) * 128 + loff);
        asm("v_fma_mix_f32 %[d], %[s0], %[s1], %[d] op_sel:[0,0,0] op_sel_hi:[1,1,0]"
            : [d]"+v"(a0A) : [s0]"s"(qs), [s1]"v"(rwv));
        asm("v_fma_mix_f32 %[d], %[s0], %[s1], %[d] op_sel:[0,1,0] op_sel_hi:[1,1,0]"
            : [d]"+v"(a1A) : [s0]"s"(qs), [s1]"v"(rwv));
    }
    for (; jB < cB; ++jB) {
        const unsigned q = se[s0B + jB];
        const unsigned qs = __builtin_amdgcn_readfirstlane(q);
        const unsigned rwv = *reinterpret_cast<const unsigned*>(
            rwb + (size_t)((qs >> 16) & 0xFFFu) * 128 + loff);
        asm("v_fma_mix_f32 %[d], %[s0], %[s1], %[d] op_sel:[0,0,0] op_sel_hi:[1,1,0]"
            : [d]"+v"(a0B) : [s0]"s"(qs), [s1]"v"(rwv));
        asm("v_fma_mix_f32 %[d], %[s0], %[s1], %[d] op_sel:[0,1,0] op_sel_hi:[1,1,0]"
            : [d]"+v"(a1B) : [s0]"s"(qs), [s1]"v"(rwv));
    }
    // exact overflow contributions (novf == 0 in practice)
    for (int k = 0; k < novf; ++k) {
        const uint2 o = ovf[k];
        if ((int)(o.x >> 16) == b) {
            const int ole = (int)((o.x >> 12) & 15u);
            if (ole == leA || ole == leB) {
                const int orel = (int)(o.x & 0xFFFu);
                const float ov = __uint_as_float(o.y);
                const unsigned orw = *reinterpret_cast<const unsigned*>(
                    rwb + (size_t)orel * 128 + loff);
                const half2v oh = __builtin_bit_cast(half2v, orw);
                if (ole == leA) { a0A += ov * (float)oh[0]; a1A += ov * (float)oh[1]; }
                else            { a0B += ov * (float)oh[0]; a1B += ov * (float)oh[1]; }
            }
        }
    }
    {
        const int ventA = b * EPB + leA;
        if (ventA < NUMENT) {
            float* op = out + (size_t)ventA * 128 + loff;
            float2 o2; o2.x = fmaxf(a0A, 0.f); o2.y = fmaxf(a1A, 0.f);
            *reinterpret_cast<float2*>(op) = o2;
        }
        const int ventB = b * EPB + leB;
        if (ventB < NUMENT) {
            float* op = out + (size_t)ventB * 128 + loff;
            float2 o2; o2.x = fmaxf(a0B, 0.f); o2.y = fmaxf(a1B, 0.f);
            *reinterpret_cast<float2*>(op) = o2;
        }
    }
}

// ---------------------------------------------------------------------------
// Fallback path (ws too small / shape out of range): direct vector scatter.
// ---------------------------------------------------------------------------
__global__ void rwb_f32_kernel(const float* __restrict__ rel, const float* __restrict__ W,
                               const float* __restrict__ b, float* __restrict__ rwb, int R) {
    const int k = blockIdx.x;
    const int n = threadIdx.x;
    __shared__ float relk[128];
    relk[n] = rel[(size_t)k * 128 + n];
    __syncthreads();
    const float4* w4 = reinterpret_cast<const float4*>(W + (size_t)n * 128);
    const float4* r4 = reinterpret_cast<const float4*>(relk);
    float acc = 0.f;
#pragma unroll
    for (int i = 0; i < 32; ++i) {
        float4 a = r4[i], w = w4[i];
        acc += a.x * w.x + a.y * w.y + a.z * w.z + a.w * w.w;
    }
    rwb[(size_t)k * 128 + n] = acc + b[n];
}

__global__ void scatter_vec_kernel(const int* __restrict__ heads, const int* __restrict__ tails,
                                   const int* __restrict__ rels, const float* __restrict__ val,
                                   const float* __restrict__ rwb, float* __restrict__ out,
                                   long long nitems) {
    const long long i = (long long)blockIdx.x * blockDim.x + threadIdx.x;
    if (i >= nitems) return;
    const int e = (int)(i >> 5);
    const int c = (int)(i & 31) * 4;
    const float v = val[e];
    float4 rw = *reinterpret_cast<const float4*>(rwb + (size_t)rels[e] * 128 + c);
    float* pt = out + (size_t)tails[e] * 128 + c;
    float* ph = out + (size_t)heads[e] * 128 + c;
    unsafeAtomicAdd(pt + 0, v * rw.x); unsafeAtomicAdd(pt + 1, v * rw.y);
    unsafeAtomicAdd(pt + 2, v * rw.z); unsafeAtomicAdd(pt + 3, v * rw.w);
    unsafeAtomicAdd(ph + 0, v * rw.x); unsafeAtomicAdd(ph + 1, v * rw.y);
    unsafeAtomicAdd(ph + 2, v * rw.z); unsafeAtomicAdd(ph + 3, v * rw.w);
}

__global__ void relu_kernel(float* __restrict__ out, int n4) {
    const int i = blockIdx.x * blockDim.x + threadIdx.x;
    if (i >= n4) return;
    float4* p = reinterpret_cast<float4*>(out) + i;
    float4 v = *p;
    v.x = fmaxf(v.x, 0.f); v.y = fmaxf(v.y, 0.f);
    v.z = fmaxf(v.z, 0.f); v.w = fmaxf(v.w, 0.f);
    *p = v;
}

// ---------------------------------------------------------------------------
extern "C" void kernel_launch(void* const* d_in, const int* in_sizes, int n_in,
                              void* d_out, int out_size, void* d_ws, size_t ws_size,
                              hipStream_t stream) {
    // inputs: 0 local_entity [B*M] (shape only), 1 heads [E], 2 tails [E],
    //         3 rels [E], 4 val [E], 5 rel_features [R*D], 6 W [D*D], 7 b [D]
    const int* heads = (const int*)d_in[1];
    const int* tails = (const int*)d_in[2];
    const int* rels  = (const int*)d_in[3];
    const float* val  = (const float*)d_in[4];
    const float* relf = (const float*)d_in[5];
    const float* W    = (const float*)d_in[6];
    const float* b    = (const float*)d_in[7];
    float* out = (float*)d_out;

    const int NUMENT = in_sizes[0];          // 16000
    const int E      = in_sizes[1];          // 2,000,000
    const int D      = in_sizes[7];          // 128
    const int R      = in_sizes[5] / D;      // 2000

    const int NB = (NUMENT + EPB - 1) / EPB; // 1000 buckets
    const long long mean = (2LL * E * EPB) / (NUMENT > 0 ? NUMENT : 1);
    int CAPB = (int)(mean + mean / 16 + 256);

    // ws layout: rwb | ctrl { gcnt[NB], ovfcnt } | ovf[OVFCAP] | slots
    const size_t rwb_bytes = (size_t)R * D * sizeof(_Float16);          // 512 KB
    const size_t off_ctrl  = (rwb_bytes + 255) & ~(size_t)255;
    const size_t ctrl_b    = (size_t)(NB + 1) * sizeof(int);
    const size_t off_ovf   = (off_ctrl + ctrl_b + 255) & ~(size_t)255;
    const size_t ovf_b     = (size_t)OVFCAP * sizeof(uint2);            // 512 KB
    const size_t off_slots = (off_ovf + ovf_b + 255) & ~(size_t)255;
    const size_t slots_b   = (size_t)NB * CAPB * sizeof(unsigned);      // ~18 MB

    if (NB <= MAXNB && R < 4096 && CAPB <= SORTCAP &&
        ws_size >= off_slots + slots_b) {
        _Float16* rwb   = (_Float16*)d_ws;
        int* gcnt       = (int*)((char*)d_ws + off_ctrl);
        int* ovfcnt     = gcnt + NB;
        uint2* ovf      = (uint2*)((char*)d_ws + off_ovf);
        unsigned* slots = (unsigned*)((char*)d_ws + off_slots);

        hipMemsetAsync(gcnt, 0, ctrl_b, stream);     // gcnt + ovfcnt (4 KB)
        bin_rwb_kernel<<<(E + FPB - 1) / FPB, 1024, 0, stream>>>(
            heads, tails, rels, val, relf, W, b, rwb,
            gcnt, ovfcnt, ovf, slots, E, R, NB, CAPB);
        gather_kernel<<<NB, 512, 0, stream>>>(
            slots, gcnt, ovfcnt, ovf, rwb, out, NUMENT, CAPB);
    } else {
        // fallback: accumulate directly into out (slow but small-ws safe)
        float* rwb = (float*)d_ws;           // R*D fp32 (~1 MB)
        hipMemsetAsync(out, 0, (size_t)out_size * sizeof(float), stream);
        rwb_f32_kernel<<<R, 128, 0, stream>>>(relf, W, b, rwb, R);
        const long long items = (long long)E * 32;
        scatter_vec_kernel<<<(unsigned)((items + 255) / 256), 256, 0, stream>>>(
            heads, tails, rels, val, rwb, out, items);
        relu_kernel<<<(out_size / 4 + 255) / 256, 256, 0, stream>>>(out, out_size / 4);
    }
}